// Round 17
// baseline (715.019 us; speedup 1.0000x reference)
//
#include <hip/hip_runtime.h>

#define NN   100000
#define NEDG 800000
#define NG   1000
#define HD   128
#define EDIM 64

#define NB3 (NEDG / 64)        // 12500 k3 blocks
#define NB2 ((NN + 63) / 64)   // 1563  k2 blocks
#define NB6 ((NN + 63) / 64)   // 1563  k6 blocks
#define NB4 (NN / 32)          // 3125  k4 blocks
#define W0B 108                // wconv blocks (27648/256)
#define MH_HIST 3125           // hist blocks
#define Z_F4 3200000           // sve float4 count
#define Z_EXTRA 100001         // cnt ints + tick
#define ZB ((Z_F4 + Z_EXTRA + 255) / 256)
#define M0_GRID (W0B + NG + ZB)
#define NSCB 98

typedef unsigned short u16;
typedef __bf16 bf16x8 __attribute__((ext_vector_type(8)));
typedef float f32x4 __attribute__((ext_vector_type(4)));
typedef u16 u16x8 __attribute__((ext_vector_type(8)));
typedef unsigned u32x4 __attribute__((ext_vector_type(4)));

#define MFMA16(a, b, c) __builtin_amdgcn_mfma_f32_16x16x32_bf16(a, b, c, 0, 0, 0)

#define WS_E    0
#define WS_GA   4096
#define WS_WIH  6144
#define WS_WHH  12288
#define WS_MA0  18432
#define WS_KW   26624
#define WS_LANES 27648

#define BF(base, NTT, ks, nt, lane) \
    (*(const bf16x8*)(wsw + (size_t)((base) + (((ks) * (NTT) + (nt)) * 64 + (lane))) * 8))

__device__ __forceinline__ float sigmoidf_(float x) { return 1.0f / (1.0f + __expf(-x)); }
__device__ __forceinline__ float tanhf_(float x) {
    float ax = fabsf(x);
    float e  = __expf(-2.0f * ax);
    float t  = (1.0f - e) / (1.0f + e);
    return copysignf(t, x);
}
__device__ __forceinline__ float leaky_(float x) { return x >= 0.f ? x : 0.1f * x; }
__device__ __forceinline__ u16 f2bf(float x) {
    union { float f; unsigned u; } c; c.f = x;
    unsigned r = c.u + 0x7FFF + ((c.u >> 16) & 1);
    return (u16)(r >> 16);
}
__device__ __forceinline__ float bfbits2f(unsigned hw) {
    union { unsigned u; float f; } c; c.u = hw << 16; return c.f;
}
__device__ __forceinline__ unsigned pack2bf(float lo, float hi) {
    return (unsigned)f2bf(lo) | ((unsigned)f2bf(hi) << 16);
}
__device__ __forceinline__ bf16x8 mk8(const float* __restrict__ p) {
    float4 a = *(const float4*)p;
    float4 b = *(const float4*)(p + 4);
    union { u32x4 u; bf16x8 v; } c;
    c.u[0] = pack2bf(a.x, a.y);
    c.u[1] = pack2bf(a.z, a.w);
    c.u[2] = pack2bf(b.x, b.y);
    c.u[3] = pack2bf(b.z, b.w);
    return c.v;
}

__device__ __forceinline__ void stg1(u16* lds, int P, int r, int c, u16 val) {
    int byteoff = (c << 1) ^ ((r & 7) << 4);
    lds[r * P + (byteoff >> 1)] = val;
}
__device__ __forceinline__ bf16x8 ldA(const u16* lds, int P, int r, int ks, int hi) {
    int byteoff = (ks * 64 + (hi << 4)) ^ ((r & 7) << 4);
    return *(const bf16x8*)(lds + r * P + (byteoff >> 1));
}

// ---------------- wconv body --------------------------------------------------
__device__ __forceinline__ void wconv_body(
    int t,
    const float* __restrict__ E_w, const float* __restrict__ gmA_w,
    const float* __restrict__ Wih, const float* __restrict__ Whh,
    const float* __restrict__ mA_w, const float* __restrict__ K_w,
    u16* __restrict__ dst)
{
    const float* W; int N; int local;
    if (t < 4096)       { W = E_w;  N = 128; local = t; }
    else if (t < 6144)  { W = gmA_w; N = 128; local = t - 4096; }
    else if (t < 12288) { W = Wih;  N = 384; local = t - 6144; }
    else if (t < 18432) { W = Whh;  N = 384; local = t - 12288; }
    else if (t < 26624) { int k = (t - 18432) >> 11; W = mA_w + k * 128 * 128; N = 128; local = (t - 18432) & 2047; }
    else                { W = K_w;  N = 128; local = t - 26624; }
    int lane = local & 63;
    int fid  = local >> 6;
    int NT = N >> 4;
    int ks = fid / NT, nt = fid - ks * NT;
    int krow = ks * 32 + ((lane >> 4) << 3);
    int col  = nt * 16 + (lane & 15);
    u16* d = dst + (size_t)t * 8;
    #pragma unroll
    for (int j = 0; j < 8; j++) d[j] = f2bf(W[(size_t)(krow + j) * N + col]);
}

// ---------------- k1 body (256 threads; upper half zeroes vbar/denom) ---------
__device__ __forceinline__ void k1_body(
    int g, int t,
    const float* __restrict__ s,
    const float* __restrict__ A_w, const float* __restrict__ A_b,
    const float* __restrict__ mB_w, const float* __restrict__ mB_b,
    const float* __restrict__ mC_w,
    const float* __restrict__ C_w, const float* __restrict__ C_b,
    const float* __restrict__ gmB_w, const float* __restrict__ gmA_b, const float* __restrict__ gmB_b,
    float* __restrict__ s2s, float* __restrict__ wkg,
    float* __restrict__ s2m_tab, float* __restrict__ t2,
    float* __restrict__ vbar, float* __restrict__ denom)
{
    __shared__ float sm[HD];
    __shared__ float sm2[HD];
    if (t < HD) sm[t] = s[g * HD + t];
    else {
        int i = t - 128;
        #pragma unroll
        for (int j = 0; j < 4; j++) vbar[(size_t)g * 512 + i + 128 * j] = 0.f;
        if (i < 4) denom[g * 4 + i] = 0.f;
    }
    __syncthreads();
    float s2m = 0.f;
    if (t < HD) {
        {
            float a = 0.f;
            #pragma unroll 8
            for (int i = 0; i < HD; i++) a = fmaf(sm[i], A_w[i * HD + t], a);
            s2s[g * HD + t] = tanhf_(a + A_b[t]);
        }
        for (int k = 0; k < 4; k++) {
            float a = 0.f;
            const float* W = mB_w + k * HD * HD;
            #pragma unroll 8
            for (int i = 0; i < HD; i++) a = fmaf(sm[i], W[i * HD + t], a);
            float d = tanhf_(a + mB_b[k * HD + t]);
            wkg[(k * NG + g) * HD + t] = d * mC_w[k * HD + t];
        }
        {
            float a = 0.f;
            #pragma unroll 8
            for (int i = 0; i < HD; i++) a = fmaf(sm[i], C_w[i * HD + t], a);
            s2m = tanhf_(a + C_b[t]);
            s2m_tab[g * HD + t] = s2m;
            sm2[t] = s2m;
        }
    }
    __syncthreads();
    if (t < HD) {
        float a = 0.f;
        #pragma unroll 8
        for (int i = 0; i < HD; i++) a = fmaf(sm2[i], gmB_w[i * HD + t], a);
        t2[g * HD + t] = a + gmA_b[t] + gmB_b[t];
    }
}

// ---------------- Mega0: wconv | k1+zero | zero sve/cnt/tick ------------------
__global__ __launch_bounds__(256) void mega0(
    const float* __restrict__ E_w, const float* __restrict__ gmA_w,
    const float* __restrict__ Wih, const float* __restrict__ Whh,
    const float* __restrict__ mA_w, const float* __restrict__ K_w,
    u16* __restrict__ wswz,
    const float* __restrict__ s,
    const float* __restrict__ A_w, const float* __restrict__ A_b,
    const float* __restrict__ mB_w, const float* __restrict__ mB_b,
    const float* __restrict__ mC_w,
    const float* __restrict__ C_w, const float* __restrict__ C_b,
    const float* __restrict__ gmB_w, const float* __restrict__ gmA_b, const float* __restrict__ gmB_b,
    float* __restrict__ s2s, float* __restrict__ wkg,
    float* __restrict__ s2m_tab, float* __restrict__ t2,
    float* __restrict__ vbar, float* __restrict__ denom,
    float* __restrict__ sve, int* __restrict__ cnt, int* __restrict__ tick)
{
    const int bid = blockIdx.x, tid = threadIdx.x;
    if (bid < W0B) {
        wconv_body(bid * 256 + tid, E_w, gmA_w, Wih, Whh, mA_w, K_w, wswz);
    } else if (bid < W0B + NG) {
        k1_body(bid - W0B, tid, s, A_w, A_b, mB_w, mB_b, mC_w, C_w, C_b,
                gmB_w, gmA_b, gmB_b, s2s, wkg, s2m_tab, t2, vbar, denom);
    } else {
        long idx = (long)(bid - W0B - NG) * 256 + tid;
        if (idx < Z_F4) ((float4*)sve)[idx] = make_float4(0.f, 0.f, 0.f, 0.f);
        else {
            long j = idx - Z_F4;
            if (j < 100000) cnt[j] = 0;
            else if (j == 100000) tick[0] = 0;
        }
    }
}

// ---------------- K2 body: attention scores, direct global A-frags ------------
__device__ __forceinline__ void k2_body(
    int bid, int tid,
    const float* __restrict__ v, const int* __restrict__ ngr,
    const u16* __restrict__ wsw,
    const float* __restrict__ mA_b, const float* __restrict__ mC_b,
    const float* __restrict__ wkg,
    float* __restrict__ aexp, float* __restrict__ denom)
{
    const int lane = tid & 63, w = tid >> 6;
    const int l15 = lane & 15, hi = lane >> 4;
    const int n0 = bid * 64 + w * 16;
    const int arow = min(n0 + l15, NN - 1);
    bf16x8 av[4];
    #pragma unroll
    for (int ks = 0; ks < 4; ks++)
        av[ks] = mk8(v + (size_t)arow * HD + ks * 32 + hi * 8);
    int gq[4], nodeq[4];
    #pragma unroll
    for (int q = 0; q < 4; q++) {
        int nd = n0 + hi * 4 + q;
        nodeq[q] = nd;
        gq[q] = ngr[min(nd, NN - 1)];
    }
    for (int k = 0; k < 4; k++) {
        float rs[4] = {0.f, 0.f, 0.f, 0.f};
        const float* bias = mA_b + k * HD;
        #pragma unroll
        for (int nt = 0; nt < 8; nt++) {
            f32x4 acc = {0.f, 0.f, 0.f, 0.f};
            #pragma unroll
            for (int ks = 0; ks < 4; ks++)
                acc = MFMA16(av[ks], BF(WS_MA0 + k * 2048, 8, ks, nt, lane), acc);
            int col = nt * 16 + l15;
            float bb = bias[col];
            #pragma unroll
            for (int q = 0; q < 4; q++)
                rs[q] += tanhf_(acc[q] + bb) * wkg[((size_t)k * NG + gq[q]) * HD + col];
        }
        #pragma unroll
        for (int q = 0; q < 4; q++) {
            float x = rs[q];
            x += __shfl_xor(x, 1); x += __shfl_xor(x, 2);
            x += __shfl_xor(x, 4); x += __shfl_xor(x, 8);
            if (l15 == 0 && nodeq[q] < NN) {
                float ev = __expf(x + mC_b[k]);
                aexp[(size_t)nodeq[q] * 4 + k] = ev;
                atomicAdd(&denom[gq[q] * 4 + k], ev);
            }
        }
    }
}

// ---------------- MegaH: hist blocks | k2 blocks ------------------------------
__global__ __launch_bounds__(256) void megaH(
    const int* __restrict__ edst, int* __restrict__ cnt,
    const float* __restrict__ v, const int* __restrict__ ngr,
    const u16* __restrict__ wsw,
    const float* __restrict__ mA_b, const float* __restrict__ mC_b,
    const float* __restrict__ wkg,
    float* __restrict__ aexp, float* __restrict__ denom)
{
    const int bid = blockIdx.x, tid = threadIdx.x;
    if (bid < MH_HIST) {
        int i = bid * 256 + tid;
        if (i < NEDG) atomicAdd(&cnt[edst[i]], 1);
    } else {
        k2_body(bid - MH_HIST, tid, v, ngr, wsw, mA_b, mC_b, wkg, aexp, denom);
    }
}

// ---------------- scan12: scan1 + last-block serial scan2 ---------------------
__global__ __launch_bounds__(256) void k_scan12(
    const int* __restrict__ cnt,
    int* __restrict__ excl, int* __restrict__ bsum, int* __restrict__ tick)
{
    __shared__ int sd[256];
    __shared__ int amlast;
    int t = threadIdx.x, b = blockIdx.x;
    int base = b * 1024 + t * 4;
    int v0 = (base + 0 < NN) ? cnt[base + 0] : 0;
    int v1 = (base + 1 < NN) ? cnt[base + 1] : 0;
    int v2 = (base + 2 < NN) ? cnt[base + 2] : 0;
    int v3 = (base + 3 < NN) ? cnt[base + 3] : 0;
    int s = v0 + v1 + v2 + v3;
    sd[t] = s;
    __syncthreads();
    for (int off = 1; off < 256; off <<= 1) {
        int x = (t >= off) ? sd[t - off] : 0;
        __syncthreads();
        sd[t] += x;
        __syncthreads();
    }
    int incl = sd[t];
    int ex = incl - s;
    if (base + 0 < NN) excl[base + 0] = ex;
    if (base + 1 < NN) excl[base + 1] = ex + v0;
    if (base + 2 < NN) excl[base + 2] = ex + v0 + v1;
    if (base + 3 < NN) excl[base + 3] = ex + v0 + v1 + v2;
    if (t == 255) bsum[b] = incl;
    // last-block ticket: exactly one block performs the serial bsum scan
    __threadfence();
    if (t == 0) amlast = (atomicAdd(tick, 1) == NSCB - 1) ? 1 : 0;
    __syncthreads();
    if (t == 0 && amlast) {
        __threadfence();
        int run = 0;
        for (int i = 0; i < NSCB; i++) { int tv = bsum[i]; bsum[i] = run; run += tv; }
        __threadfence();
    }
}

// ---------------- scatter_fused: inline base + rank via atomicSub(cnt) --------
__global__ __launch_bounds__(256) void k_scatter_fused(
    const int* __restrict__ edst,
    const int* __restrict__ excl, const int* __restrict__ bsum,
    int* __restrict__ cnt, int* __restrict__ perm)
{
    int i = blockIdx.x * 256 + threadIdx.x;
    if (i < NEDG) {
        int d = edst[i];
        int rank = atomicSub(&cnt[d], 1) - 1;
        perm[excl[d] + bsum[d >> 10] + rank] = i;
    }
}

// ---------------- K3 body: dst-sorted merge, direct e-frag loads --------------
#define OPW 66
__device__ __forceinline__ void k3_body(
    int bid, int tid, char* SM,
    const float* __restrict__ e, const float* __restrict__ v,
    const int* __restrict__ esrc, const int* __restrict__ edst,
    const int* __restrict__ perm,
    const u16* __restrict__ wsw, const float* __restrict__ K_b,
    float* __restrict__ sve)
{
    unsigned* OUTP = (unsigned*)SM;                    // 16896 B
    int* pid  = (int*)(SM + 16896);                    // 256 B
    int* dsta = pid + 64;                              // 256 B
    const int e0 = bid * 64;
    if (tid < 64) {
        int p = perm[e0 + tid];
        pid[tid] = p;
        dsta[tid] = edst[p];
    }
    const int lane = tid & 63, w = tid >> 6;
    const int l15 = lane & 15, hi = lane >> 4;
    const int rbase = w * 16;
    const int myrow = perm[e0 + rbase + l15];
    bf16x8 ae[2];
    #pragma unroll
    for (int ks = 0; ks < 2; ks++)
        ae[ks] = mk8(e + (size_t)myrow * EDIM + ks * 32 + hi * 8);
    __syncthreads();
    int sq[4];
    #pragma unroll
    for (int q = 0; q < 4; q++) sq[q] = esrc[pid[rbase + hi * 4 + q]];
    u16* OU = (u16*)OUTP;
    #pragma unroll
    for (int nt = 0; nt < 8; nt++) {
        f32x4 acc = {0.f, 0.f, 0.f, 0.f};
        acc = MFMA16(ae[0], BF(WS_KW, 8, 0, nt, lane), acc);
        acc = MFMA16(ae[1], BF(WS_KW, 8, 1, nt, lane), acc);
        int col = nt * 16 + l15;
        float kb = K_b[col];
        #pragma unroll
        for (int q = 0; q < 4; q++) {
            float val = leaky_((acc[q] + kb) * v[(size_t)sq[q] * HD + col]);
            OU[(rbase + hi * 4 + q) * (OPW * 2) + col] = f2bf(val);
        }
    }
    __syncthreads();
    {
        const int cp = tid & 63;
        const int qr = tid >> 6;
        const int r0 = qr * 16;
        int dcur = dsta[r0];
        unsigned x = OUTP[r0 * OPW + cp];
        float a0 = bfbits2f(x & 0xffff), a1 = bfbits2f(x >> 16);
        #pragma unroll
        for (int i = 1; i < 16; i++) {
            int r = r0 + i;
            int d = dsta[r];
            unsigned y = OUTP[r * OPW + cp];
            float y0 = bfbits2f(y & 0xffff), y1 = bfbits2f(y >> 16);
            if (d == dcur) { a0 += y0; a1 += y1; }
            else {
                atomicAdd(&sve[(size_t)dcur * HD + cp * 2 + 0], a0);
                atomicAdd(&sve[(size_t)dcur * HD + cp * 2 + 1], a1);
                dcur = d; a0 = y0; a1 = y1;
            }
        }
        atomicAdd(&sve[(size_t)dcur * HD + cp * 2 + 0], a0);
        atomicAdd(&sve[(size_t)dcur * HD + cp * 2 + 1], a1);
    }
}

// ---------------- K4 body: vbar ----------------------------------------------
__device__ __forceinline__ void k4_body(
    int bid, int tid,
    const float* __restrict__ v, const int* __restrict__ ngr,
    const float* __restrict__ aexp, const float* __restrict__ denom,
    float* __restrict__ vbar)
{
    const int d = tid & 127;
    const int hf = tid >> 7;
    const int n0 = bid * 32 + hf * 16;
    int gcur = -1;
    float a0 = 0.f, a1 = 0.f, a2 = 0.f, a3 = 0.f;
    float4 rd = make_float4(0.f, 0.f, 0.f, 0.f);
    for (int nd = 0; nd < 16; nd++) {
        int n = n0 + nd;
        int g = ngr[n];
        if (g != gcur) {
            if (gcur >= 0) {
                atomicAdd(&vbar[(gcur * 4 + 0) * HD + d], a0);
                atomicAdd(&vbar[(gcur * 4 + 1) * HD + d], a1);
                atomicAdd(&vbar[(gcur * 4 + 2) * HD + d], a2);
                atomicAdd(&vbar[(gcur * 4 + 3) * HD + d], a3);
                a0 = a1 = a2 = a3 = 0.f;
            }
            float4 dn = *(const float4*)&denom[g * 4];
            rd = make_float4(1.f / dn.x, 1.f / dn.y, 1.f / dn.z, 1.f / dn.w);
            gcur = g;
        }
        float4 ae = *(const float4*)&aexp[n * 4];
        float vv = v[(size_t)n * HD + d];
        a0 = fmaf(ae.x * rd.x, vv, a0);
        a1 = fmaf(ae.y * rd.y, vv, a1);
        a2 = fmaf(ae.z * rd.z, vv, a2);
        a3 = fmaf(ae.w * rd.w, vv, a3);
    }
    atomicAdd(&vbar[(gcur * 4 + 0) * HD + d], a0);
    atomicAdd(&vbar[(gcur * 4 + 1) * HD + d], a1);
    atomicAdd(&vbar[(gcur * 4 + 2) * HD + d], a2);
    atomicAdd(&vbar[(gcur * 4 + 3) * HD + d], a3);
}

// ---------------- Mega3: k3 blocks then k4 backfill ---------------------------
__global__ __launch_bounds__(256) void mega3(
    const float* __restrict__ e, const float* __restrict__ v,
    const int* __restrict__ esrc, const int* __restrict__ edst,
    const int* __restrict__ perm,
    const u16* __restrict__ wsw, const float* __restrict__ K_b,
    float* __restrict__ sve,
    const int* __restrict__ ngr,
    const float* __restrict__ aexp, const float* __restrict__ denom,
    float* __restrict__ vbar)
{
    __shared__ __align__(16) char SM[17408];
    const int bid = blockIdx.x, tid = threadIdx.x;
    if (bid < NB3) {
        k3_body(bid, tid, SM, e, v, esrc, edst, perm, wsw, K_b, sve);
    } else {
        k4_body(bid - NB3, tid, v, ngr, aexp, denom, vbar);
    }
}

// ---------------- K3 fallback: unsorted (global atomics, direct loads) --------
__global__ __launch_bounds__(256) void k3_edge_unsorted(
    const float* __restrict__ e, const float* __restrict__ v,
    const int* __restrict__ esrc, const int* __restrict__ edst,
    const u16* __restrict__ wsw, const float* __restrict__ K_b,
    float* __restrict__ sve)
{
    const int tid = threadIdx.x;
    const int e0 = blockIdx.x * 64;
    const int lane = tid & 63, w = tid >> 6;
    const int l15 = lane & 15, hi = lane >> 4;
    const int rbase = w * 16;
    const int myrow = e0 + rbase + l15;
    bf16x8 ae[2];
    #pragma unroll
    for (int ks = 0; ks < 2; ks++)
        ae[ks] = mk8(e + (size_t)myrow * EDIM + ks * 32 + hi * 8);
    int sq[4], dq[4];
    #pragma unroll
    for (int q = 0; q < 4; q++) {
        int ei = e0 + rbase + hi * 4 + q;
        sq[q] = esrc[ei]; dq[q] = edst[ei];
    }
    #pragma unroll
    for (int nt = 0; nt < 8; nt++) {
        f32x4 acc = {0.f, 0.f, 0.f, 0.f};
        acc = MFMA16(ae[0], BF(WS_KW, 8, 0, nt, lane), acc);
        acc = MFMA16(ae[1], BF(WS_KW, 8, 1, nt, lane), acc);
        int col = nt * 16 + l15;
        float kb = K_b[col];
        #pragma unroll
        for (int q = 0; q < 4; q++) {
            float val = leaky_((acc[q] + kb) * v[(size_t)sq[q] * HD + col]);
            atomicAdd(&sve[(size_t)dq[q] * HD + col], val);
        }
    }
}

__global__ __launch_bounds__(256) void k4_standalone(
    const float* __restrict__ v, const int* __restrict__ ngr,
    const float* __restrict__ aexp, const float* __restrict__ denom,
    float* __restrict__ vbar)
{
    k4_body(blockIdx.x, threadIdx.x, v, ngr, aexp, denom, vbar);
}

// ---------------- K6 body: node update, packed bf16 state ---------------------
__device__ __forceinline__ void k6_body(
    int bid, int tid, u16* T,
    const float* __restrict__ v, const int* __restrict__ ngr,
    const float* __restrict__ sve, const u16* __restrict__ wsw,
    const float* __restrict__ E_b,
    const float* __restrict__ s2m_tab, const float* __restrict__ t2,
    const float* __restrict__ bih, const float* __restrict__ bhh,
    float* __restrict__ out_v)
{
    const int lane = tid & 63;
    const int l15 = lane & 15, hi = lane >> 4;
    const int n0 = bid * 64 + (tid >> 6) * 16;
    const int arow = min(n0 + l15, NN - 1);
    bf16x8 av[4], ax[4];
    #pragma unroll
    for (int ks = 0; ks < 4; ks++) {
        av[ks] = mk8(v   + (size_t)arow * HD + ks * 32 + hi * 8);
        ax[ks] = mk8(sve + (size_t)arow * HD + ks * 32 + hi * 8);
    }
    int gq[4], nodeq[4];
    #pragma unroll
    for (int q = 0; q < 4; q++) {
        int nd = n0 + hi * 4 + q;
        nodeq[q] = nd;
        gq[q] = ngr[min(nd, NN - 1)];
    }
    unsigned m2mp[8][2];
    #pragma unroll
    for (int nt = 0; nt < 8; nt++) {
        f32x4 acc = {0.f, 0.f, 0.f, 0.f};
        #pragma unroll
        for (int ks = 0; ks < 4; ks++) acc = MFMA16(ax[ks], BF(WS_E, 8, ks, nt, lane), acc);
        #pragma unroll
        for (int ks = 0; ks < 4; ks++) acc = MFMA16(av[ks], BF(WS_E, 8, 4 + ks, nt, lane), acc);
        float eb = E_b[nt * 16 + l15];
        float m0 = leaky_(acc[0] + eb), m1 = leaky_(acc[1] + eb);
        float m2 = leaky_(acc[2] + eb), m3 = leaky_(acc[3] + eb);
        m2mp[nt][0] = pack2bf(m0, m1);
        m2mp[nt][1] = pack2bf(m2, m3);
        int col = nt * 16 + l15;
        stg1(T, 128, hi * 4 + 0, col, (u16)(m2mp[nt][0] & 0xffff));
        stg1(T, 128, hi * 4 + 1, col, (u16)(m2mp[nt][0] >> 16));
        stg1(T, 128, hi * 4 + 2, col, (u16)(m2mp[nt][1] & 0xffff));
        stg1(T, 128, hi * 4 + 3, col, (u16)(m2mp[nt][1] >> 16));
    }
    bf16x8 am[4];
    #pragma unroll
    for (int ks = 0; ks < 4; ks++) am[ks] = ldA(T, 128, l15, ks, hi);
    unsigned hmp[8][2];
    #pragma unroll
    for (int nt = 0; nt < 8; nt++) {
        f32x4 acc = {0.f, 0.f, 0.f, 0.f};
        #pragma unroll
        for (int ks = 0; ks < 4; ks++) acc = MFMA16(am[ks], BF(WS_GA, 8, ks, nt, lane), acc);
        int col = nt * 16 + l15;
        float m2mq[4] = { bfbits2f(m2mp[nt][0] & 0xffff), bfbits2f(m2mp[nt][0] >> 16),
                          bfbits2f(m2mp[nt][1] & 0xffff), bfbits2f(m2mp[nt][1] >> 16) };
        float hm[4];
        #pragma unroll
        for (int q = 0; q < 4; q++) {
            int g = gq[q];
            float z = sigmoidf_(acc[q] + t2[(size_t)g * HD + col]);
            hm[q] = z * s2m_tab[(size_t)g * HD + col] + (1.f - z) * m2mq[q];
        }
        hmp[nt][0] = pack2bf(hm[0], hm[1]);
        hmp[nt][1] = pack2bf(hm[2], hm[3]);
        stg1(T, 128, hi * 4 + 0, col, (u16)(hmp[nt][0] & 0xffff));
        stg1(T, 128, hi * 4 + 1, col, (u16)(hmp[nt][0] >> 16));
        stg1(T, 128, hi * 4 + 2, col, (u16)(hmp[nt][1] & 0xffff));
        stg1(T, 128, hi * 4 + 3, col, (u16)(hmp[nt][1] >> 16));
    }
    bf16x8 ah[4];
    #pragma unroll
    for (int ks = 0; ks < 4; ks++) ah[ks] = ldA(T, 128, l15, ks, hi);
    #pragma unroll
    for (int nt = 0; nt < 8; nt++) {
        f32x4 air = {0.f,0.f,0.f,0.f}, aiz = {0.f,0.f,0.f,0.f}, ain = {0.f,0.f,0.f,0.f};
        f32x4 ahr = {0.f,0.f,0.f,0.f}, ahz = {0.f,0.f,0.f,0.f}, ahn = {0.f,0.f,0.f,0.f};
        #pragma unroll
        for (int ks = 0; ks < 4; ks++) {
            air = MFMA16(av[ks], BF(WS_WIH, 24, ks, nt,      lane), air);
            ahr = MFMA16(ah[ks], BF(WS_WHH, 24, ks, nt,      lane), ahr);
            aiz = MFMA16(av[ks], BF(WS_WIH, 24, ks, nt + 8,  lane), aiz);
            ahz = MFMA16(ah[ks], BF(WS_WHH, 24, ks, nt + 8,  lane), ahz);
            ain = MFMA16(av[ks], BF(WS_WIH, 24, ks, nt + 16, lane), ain);
            ahn = MFMA16(ah[ks], BF(WS_WHH, 24, ks, nt + 16, lane), ahn);
        }
        int col = nt * 16 + l15;
        float br  = bih[col] + bhh[col];
        float bz  = bih[HD + col] + bhh[HD + col];
        float bi3 = bih[2 * HD + col];
        float bh3 = bhh[2 * HD + col];
        float hmq[4] = { bfbits2f(hmp[nt][0] & 0xffff), bfbits2f(hmp[nt][0] >> 16),
                         bfbits2f(hmp[nt][1] & 0xffff), bfbits2f(hmp[nt][1] >> 16) };
        #pragma unroll
        for (int q = 0; q < 4; q++) {
            float r   = sigmoidf_(air[q] + ahr[q] + br);
            float z   = sigmoidf_(aiz[q] + ahz[q] + bz);
            float nnv = tanhf_(ain[q] + bi3 + r * (ahn[q] + bh3));
            if (nodeq[q] < NN)
                out_v[(size_t)nodeq[q] * HD + col] = (1.f - z) * nnv + z * hmq[q];
        }
    }
}

// ---------------- K5 body (256 threads, lower 128 active) ---------------------
__device__ __forceinline__ void k5_body(
    int g, int t, float* SM,
    const float* __restrict__ s, const float* __restrict__ vbar,
    const float* __restrict__ mD_w, const float* __restrict__ mD_b,
    const float* __restrict__ B_w, const float* __restrict__ B_b,
    const float* __restrict__ s2s,
    const float* __restrict__ gsA_w, const float* __restrict__ gsA_b,
    const float* __restrict__ gsB_w, const float* __restrict__ gsB_b,
    const float* __restrict__ gsWih, const float* __restrict__ gsWhh,
    const float* __restrict__ gsbih, const float* __restrict__ gsbhh,
    float* __restrict__ out_s)
{
    float* vb    = SM;          // 512
    float* p     = SM + 512;    // 512
    float* m2s_l = SM + 1024;   // 128
    float* s2s_l = SM + 1152;   // 128
    float* hs_l  = SM + 1280;   // 128
    float* srow  = SM + 1408;   // 128
    const bool act = t < HD;
    if (act) {
        #pragma unroll
        for (int l = 0; l < 4; l++) vb[t + HD * l] = vbar[(size_t)g * 4 * HD + t + HD * l];
        srow[t]  = s[g * HD + t];
        s2s_l[t] = s2s[g * HD + t];
    }
    __syncthreads();
    if (act) {
        for (int k = 0; k < 4; k++) {
            float a = 0.f;
            const float* W = mD_w + k * HD * HD;
            #pragma unroll 8
            for (int i = 0; i < HD; i++) a = fmaf(vb[k * HD + i], W[i * HD + t], a);
            p[k * HD + t] = a + mD_b[k * HD + t];
        }
    }
    __syncthreads();
    float m2s = 0.f;
    if (act) {
        float a = 0.f;
        #pragma unroll 8
        for (int j = 0; j < 4 * HD; j++) a = fmaf(p[j], B_w[j * HD + t], a);
        m2s = tanhf_(a + B_b[t]);
        m2s_l[t] = m2s;
    }
    __syncthreads();
    float hs = 0.f;
    if (act) {
        float za = 0.f, zb = 0.f;
        #pragma unroll 8
        for (int i = 0; i < HD; i++) {
            za = fmaf(s2s_l[i], gsA_w[i * HD + t], za);
            zb = fmaf(m2s_l[i], gsB_w[i * HD + t], zb);
        }
        float z = sigmoidf_(za + gsA_b[t] + zb + gsB_b[t]);
        hs = z * m2s + (1.f - z) * s2s_l[t];
        hs_l[t] = hs;
    }
    __syncthreads();
    if (act) {
        float gi0 = 0.f, gh0 = 0.f, gi1 = 0.f, gh1 = 0.f, gi2 = 0.f, gh2 = 0.f;
        #pragma unroll 4
        for (int i = 0; i < HD; i++) {
            float sv = srow[i], hv = hs_l[i];
            gi0 = fmaf(sv, gsWih[i * 384 + t], gi0);
            gh0 = fmaf(hv, gsWhh[i * 384 + t], gh0);
            gi1 = fmaf(sv, gsWih[i * 384 + 128 + t], gi1);
            gh1 = fmaf(hv, gsWhh[i * 384 + 128 + t], gh1);
            gi2 = fmaf(sv, gsWih[i * 384 + 256 + t], gi2);
            gh2 = fmaf(hv, gsWhh[i * 384 + 256 + t], gh2);
        }
        float r  = sigmoidf_(gi0 + gsbih[t] + gh0 + gsbhh[t]);
        float z2 = sigmoidf_(gi1 + gsbih[128 + t] + gh1 + gsbhh[128 + t]);
        float nn = tanhf_(gi2 + gsbih[256 + t] + r * (gh2 + gsbhh[256 + t]));
        out_s[g * HD + t] = (1.f - z2) * nn + z2 * hs;
    }
}

// ---------------- Mega2b: k6 blocks then k5 backfill --------------------------
__global__ __launch_bounds__(256) void mega2b(
    const float* __restrict__ v, const int* __restrict__ ngr,
    const float* __restrict__ sve, const u16* __restrict__ wsw,
    const float* __restrict__ E_b,
    const float* __restrict__ s2m_tab, const float* __restrict__ t2,
    const float* __restrict__ bih, const float* __restrict__ bhh,
    float* __restrict__ out_v,
    const float* __restrict__ s, const float* __restrict__ vbar,
    const float* __restrict__ mD_w, const float* __restrict__ mD_b,
    const float* __restrict__ B_w, const float* __restrict__ B_b,
    const float* __restrict__ s2s,
    const float* __restrict__ gsA_w, const float* __restrict__ gsA_b,
    const float* __restrict__ gsB_w, const float* __restrict__ gsB_b,
    const float* __restrict__ gsWih, const float* __restrict__ gsWhh,
    const float* __restrict__ gsbih, const float* __restrict__ gsbhh,
    float* __restrict__ out_s)
{
    __shared__ __align__(16) char SM[16384];
    const int bid = blockIdx.x, tid = threadIdx.x;
    if (bid < NB6) {
        k6_body(bid, tid, (u16*)(SM + (tid >> 6) * 4096), v, ngr, sve, wsw,
                E_b, s2m_tab, t2, bih, bhh, out_v);
    } else {
        k5_body(bid - NB6, tid, (float*)SM, s, vbar, mD_w, mD_b, B_w, B_b, s2s,
                gsA_w, gsA_b, gsB_w, gsB_b, gsWih, gsWhh, gsbih, gsbhh, out_s);
    }
}

extern "C" void kernel_launch(void* const* d_in, const int* in_sizes, int n_in,
                              void* d_out, int out_size, void* d_ws, size_t ws_size,
                              hipStream_t stream)
{
    const float* v    = (const float*)d_in[0];
    const float* e    = (const float*)d_in[1];
    const float* s    = (const float*)d_in[2];
    const int*   esrc = (const int*)d_in[3];
    const int*   edst = (const int*)d_in[4];
    const int*   ngr  = (const int*)d_in[5];
    const float* A_w  = (const float*)d_in[6];
    const float* A_b  = (const float*)d_in[7];
    const float* mA_w = (const float*)d_in[8];
    const float* mA_b = (const float*)d_in[9];
    const float* mB_w = (const float*)d_in[10];
    const float* mB_b = (const float*)d_in[11];
    const float* mC_w = (const float*)d_in[12];
    const float* mC_b = (const float*)d_in[13];
    const float* mD_w = (const float*)d_in[14];
    const float* mD_b = (const float*)d_in[15];
    const float* B_w  = (const float*)d_in[16];
    const float* B_b  = (const float*)d_in[17];
    const float* C_w  = (const float*)d_in[18];
    const float* C_b  = (const float*)d_in[19];
    const float* K_w  = (const float*)d_in[20];
    const float* K_b  = (const float*)d_in[21];
    const float* E_w  = (const float*)d_in[22];
    const float* E_b  = (const float*)d_in[23];
    const float* gmA_w = (const float*)d_in[24];
    const float* gmA_b = (const float*)d_in[25];
    const float* gmB_w = (const float*)d_in[26];
    const float* gmB_b = (const float*)d_in[27];
    const float* gmWih = (const float*)d_in[28];
    const float* gmWhh = (const float*)d_in[29];
    const float* gmbih = (const float*)d_in[30];
    const float* gmbhh = (const float*)d_in[31];
    const float* gsA_w = (const float*)d_in[32];
    const float* gsA_b = (const float*)d_in[33];
    const float* gsB_w = (const float*)d_in[34];
    const float* gsB_b = (const float*)d_in[35];
    const float* gsWih = (const float*)d_in[36];
    const float* gsWhh = (const float*)d_in[37];
    const float* gsbih = (const float*)d_in[38];
    const float* gsbhh = (const float*)d_in[39];

    float* ws      = (float*)d_ws;
    float* sve     = ws;
    float* aexp    = sve + 12800000;
    float* denom   = aexp + 400000;
    float* wkg     = denom + 4000;
    float* s2s     = wkg + 512000;
    float* s2m_tab = s2s + 128000;
    float* t2      = s2m_tab + 128000;
    float* vbar    = t2 + 128000;
    u16*   wswz    = (u16*)(vbar + 512000);
    int*   isc     = (int*)(wswz + 221184);
    int*   cnt     = isc;
    int*   excl    = cnt + 100000;
    int*   bsum    = excl + 100000;
    int*   tick    = bsum + 128;
    int*   perm    = tick + 100000;
    const size_t NEED_SORT = ((size_t)(perm + 800000 - (int*)d_ws)) * 4;
    const bool do_sort = ws_size >= NEED_SORT;

    float* out_v = (float*)d_out;
    float* out_s = out_v + (size_t)NN * HD;

    // Mega0: wconv | k1(+vbar/denom zero) | sve/cnt/tick zero
    mega0<<<M0_GRID, 256, 0, stream>>>(E_w, gmA_w, gmWih, gmWhh, mA_w, K_w, wswz,
                                       s, A_w, A_b, mB_w, mB_b, mC_w, C_w, C_b,
                                       gmB_w, gmA_b, gmB_b, s2s, wkg, s2m_tab, t2,
                                       vbar, denom, sve, cnt, tick);
    // MegaH: hist | k2
    megaH<<<MH_HIST + NB2, 256, 0, stream>>>(edst, cnt, v, ngr, wswz, mA_b, mC_b,
                                             wkg, aexp, denom);
    if (do_sort) {
        k_scan12<<<NSCB, 256, 0, stream>>>(cnt, excl, bsum, tick);
        k_scatter_fused<<<(NEDG + 255) / 256, 256, 0, stream>>>(edst, excl, bsum, cnt, perm);
        // Mega3: k3 (12500) then k4 (3125) backfill
        mega3<<<NB3 + NB4, 256, 0, stream>>>(e, v, esrc, edst, perm, wswz, K_b, sve,
                                             ngr, aexp, denom, vbar);
    } else {
        k3_edge_unsorted<<<NEDG / 64, 256, 0, stream>>>(e, v, esrc, edst, wswz, K_b, sve);
        k4_standalone<<<NB4, 256, 0, stream>>>(v, ngr, aexp, denom, vbar);
    }
    // Mega2b: k6 (1563) then k5 (1000) backfill
    mega2b<<<NB6 + NG, 256, 0, stream>>>(v, ngr, sve, wswz, E_b, s2m_tab, t2,
                                         gmbih, gmbhh, out_v,
                                         s, vbar, mD_w, mD_b, B_w, B_b, s2s,
                                         gsA_w, gsA_b, gsB_w, gsB_b,
                                         gsWih, gsWhh, gsbih, gsbhh, out_s);
}

// Round 18
// 678.085 us; speedup vs baseline: 1.0545x; 1.0545x over previous
//
#include <hip/hip_runtime.h>

#define NN   100000
#define NEDG 800000
#define NG   1000
#define HD   128
#define EDIM 64

#define NB3 (NEDG / 64)        // 12500 k3 blocks
#define NB2 ((NN + 63) / 64)   // 1563  k2 blocks
#define NB6 ((NN + 63) / 64)   // 1563  k6 blocks
#define NB4 (NN / 32)          // 3125  k4 blocks
#define W0B 108                // wconv blocks (27648/256)
#define MH_HIST 3125           // hist blocks
#define Z_F4 3200000           // sve float4 count
#define Z_TOT 3300000          // + 100000 cnt ints
#define ZB ((Z_TOT + 255) / 256)
#define M0_GRID (W0B + NG + ZB)

typedef unsigned short u16;
typedef __bf16 bf16x8 __attribute__((ext_vector_type(8)));
typedef float f32x4 __attribute__((ext_vector_type(4)));
typedef u16 u16x8 __attribute__((ext_vector_type(8)));
typedef unsigned u32x4 __attribute__((ext_vector_type(4)));

#define MFMA16(a, b, c) __builtin_amdgcn_mfma_f32_16x16x32_bf16(a, b, c, 0, 0, 0)

#define WS_E    0
#define WS_GA   4096
#define WS_WIH  6144
#define WS_WHH  12288
#define WS_MA0  18432
#define WS_KW   26624
#define WS_LANES 27648

#define BF(base, NTT, ks, nt, lane) \
    (*(const bf16x8*)(wsw + (size_t)((base) + (((ks) * (NTT) + (nt)) * 64 + (lane))) * 8))

__device__ __forceinline__ float sigmoidf_(float x) { return 1.0f / (1.0f + __expf(-x)); }
__device__ __forceinline__ float tanhf_(float x) {
    float ax = fabsf(x);
    float e  = __expf(-2.0f * ax);
    float t  = (1.0f - e) / (1.0f + e);
    return copysignf(t, x);
}
__device__ __forceinline__ float leaky_(float x) { return x >= 0.f ? x : 0.1f * x; }
__device__ __forceinline__ u16 f2bf(float x) {
    union { float f; unsigned u; } c; c.f = x;
    unsigned r = c.u + 0x7FFF + ((c.u >> 16) & 1);
    return (u16)(r >> 16);
}
__device__ __forceinline__ float bfbits2f(unsigned hw) {
    union { unsigned u; float f; } c; c.u = hw << 16; return c.f;
}
__device__ __forceinline__ unsigned pack2bf(float lo, float hi) {
    return (unsigned)f2bf(lo) | ((unsigned)f2bf(hi) << 16);
}
__device__ __forceinline__ bf16x8 mk8(const float* __restrict__ p) {
    float4 a = *(const float4*)p;
    float4 b = *(const float4*)(p + 4);
    union { u32x4 u; bf16x8 v; } c;
    c.u[0] = pack2bf(a.x, a.y);
    c.u[1] = pack2bf(a.z, a.w);
    c.u[2] = pack2bf(b.x, b.y);
    c.u[3] = pack2bf(b.z, b.w);
    return c.v;
}

__device__ __forceinline__ void stg1(u16* lds, int P, int r, int c, u16 val) {
    int byteoff = (c << 1) ^ ((r & 7) << 4);
    lds[r * P + (byteoff >> 1)] = val;
}
__device__ __forceinline__ bf16x8 ldA(const u16* lds, int P, int r, int ks, int hi) {
    int byteoff = (ks * 64 + (hi << 4)) ^ ((r & 7) << 4);
    return *(const bf16x8*)(lds + r * P + (byteoff >> 1));
}

// ---------------- wconv body --------------------------------------------------
__device__ __forceinline__ void wconv_body(
    int t,
    const float* __restrict__ E_w, const float* __restrict__ gmA_w,
    const float* __restrict__ Wih, const float* __restrict__ Whh,
    const float* __restrict__ mA_w, const float* __restrict__ K_w,
    u16* __restrict__ dst)
{
    const float* W; int N; int local;
    if (t < 4096)       { W = E_w;  N = 128; local = t; }
    else if (t < 6144)  { W = gmA_w; N = 128; local = t - 4096; }
    else if (t < 12288) { W = Wih;  N = 384; local = t - 6144; }
    else if (t < 18432) { W = Whh;  N = 384; local = t - 12288; }
    else if (t < 26624) { int k = (t - 18432) >> 11; W = mA_w + k * 128 * 128; N = 128; local = (t - 18432) & 2047; }
    else                { W = K_w;  N = 128; local = t - 26624; }
    int lane = local & 63;
    int fid  = local >> 6;
    int NT = N >> 4;
    int ks = fid / NT, nt = fid - ks * NT;
    int krow = ks * 32 + ((lane >> 4) << 3);
    int col  = nt * 16 + (lane & 15);
    u16* d = dst + (size_t)t * 8;
    #pragma unroll
    for (int j = 0; j < 8; j++) d[j] = f2bf(W[(size_t)(krow + j) * N + col]);
}

// ---------------- k1 body (256 threads; upper half zeroes vbar/denom) ---------
__device__ __forceinline__ void k1_body(
    int g, int t,
    const float* __restrict__ s,
    const float* __restrict__ A_w, const float* __restrict__ A_b,
    const float* __restrict__ mB_w, const float* __restrict__ mB_b,
    const float* __restrict__ mC_w,
    const float* __restrict__ C_w, const float* __restrict__ C_b,
    const float* __restrict__ gmB_w, const float* __restrict__ gmA_b, const float* __restrict__ gmB_b,
    float* __restrict__ s2s, float* __restrict__ wkg,
    float* __restrict__ s2m_tab, float* __restrict__ t2,
    float* __restrict__ vbar, float* __restrict__ denom)
{
    __shared__ float sm[HD];
    __shared__ float sm2[HD];
    if (t < HD) sm[t] = s[g * HD + t];
    else {
        int i = t - 128;
        #pragma unroll
        for (int j = 0; j < 4; j++) vbar[(size_t)g * 512 + i + 128 * j] = 0.f;
        if (i < 4) denom[g * 4 + i] = 0.f;
    }
    __syncthreads();
    float s2m = 0.f;
    if (t < HD) {
        {
            float a = 0.f;
            #pragma unroll 8
            for (int i = 0; i < HD; i++) a = fmaf(sm[i], A_w[i * HD + t], a);
            s2s[g * HD + t] = tanhf_(a + A_b[t]);
        }
        for (int k = 0; k < 4; k++) {
            float a = 0.f;
            const float* W = mB_w + k * HD * HD;
            #pragma unroll 8
            for (int i = 0; i < HD; i++) a = fmaf(sm[i], W[i * HD + t], a);
            float d = tanhf_(a + mB_b[k * HD + t]);
            wkg[(k * NG + g) * HD + t] = d * mC_w[k * HD + t];
        }
        {
            float a = 0.f;
            #pragma unroll 8
            for (int i = 0; i < HD; i++) a = fmaf(sm[i], C_w[i * HD + t], a);
            s2m = tanhf_(a + C_b[t]);
            s2m_tab[g * HD + t] = s2m;
            sm2[t] = s2m;
        }
    }
    __syncthreads();
    if (t < HD) {
        float a = 0.f;
        #pragma unroll 8
        for (int i = 0; i < HD; i++) a = fmaf(sm2[i], gmB_w[i * HD + t], a);
        t2[g * HD + t] = a + gmA_b[t] + gmB_b[t];
    }
}

// ---------------- Mega0: wconv | k1+zero | zero sve/cnt -----------------------
__global__ __launch_bounds__(256) void mega0(
    const float* __restrict__ E_w, const float* __restrict__ gmA_w,
    const float* __restrict__ Wih, const float* __restrict__ Whh,
    const float* __restrict__ mA_w, const float* __restrict__ K_w,
    u16* __restrict__ wswz,
    const float* __restrict__ s,
    const float* __restrict__ A_w, const float* __restrict__ A_b,
    const float* __restrict__ mB_w, const float* __restrict__ mB_b,
    const float* __restrict__ mC_w,
    const float* __restrict__ C_w, const float* __restrict__ C_b,
    const float* __restrict__ gmB_w, const float* __restrict__ gmA_b, const float* __restrict__ gmB_b,
    float* __restrict__ s2s, float* __restrict__ wkg,
    float* __restrict__ s2m_tab, float* __restrict__ t2,
    float* __restrict__ vbar, float* __restrict__ denom,
    float* __restrict__ sve, int* __restrict__ cnt)
{
    const int bid = blockIdx.x, tid = threadIdx.x;
    if (bid < W0B) {
        wconv_body(bid * 256 + tid, E_w, gmA_w, Wih, Whh, mA_w, K_w, wswz);
    } else if (bid < W0B + NG) {
        k1_body(bid - W0B, tid, s, A_w, A_b, mB_w, mB_b, mC_w, C_w, C_b,
                gmB_w, gmA_b, gmB_b, s2s, wkg, s2m_tab, t2, vbar, denom);
    } else {
        long idx = (long)(bid - W0B - NG) * 256 + tid;
        if (idx < Z_F4) ((float4*)sve)[idx] = make_float4(0.f, 0.f, 0.f, 0.f);
        else if (idx < Z_TOT) cnt[idx - Z_F4] = 0;
    }
}

// ---------------- K2 body: attention scores, direct global A-frags ------------
__device__ __forceinline__ void k2_body(
    int bid, int tid,
    const float* __restrict__ v, const int* __restrict__ ngr,
    const u16* __restrict__ wsw,
    const float* __restrict__ mA_b, const float* __restrict__ mC_b,
    const float* __restrict__ wkg,
    float* __restrict__ aexp, float* __restrict__ denom)
{
    const int lane = tid & 63, w = tid >> 6;
    const int l15 = lane & 15, hi = lane >> 4;
    const int n0 = bid * 64 + w * 16;
    const int arow = min(n0 + l15, NN - 1);
    bf16x8 av[4];
    #pragma unroll
    for (int ks = 0; ks < 4; ks++)
        av[ks] = mk8(v + (size_t)arow * HD + ks * 32 + hi * 8);
    int gq[4], nodeq[4];
    #pragma unroll
    for (int q = 0; q < 4; q++) {
        int nd = n0 + hi * 4 + q;
        nodeq[q] = nd;
        gq[q] = ngr[min(nd, NN - 1)];
    }
    for (int k = 0; k < 4; k++) {
        float rs[4] = {0.f, 0.f, 0.f, 0.f};
        const float* bias = mA_b + k * HD;
        #pragma unroll
        for (int nt = 0; nt < 8; nt++) {
            f32x4 acc = {0.f, 0.f, 0.f, 0.f};
            #pragma unroll
            for (int ks = 0; ks < 4; ks++)
                acc = MFMA16(av[ks], BF(WS_MA0 + k * 2048, 8, ks, nt, lane), acc);
            int col = nt * 16 + l15;
            float bb = bias[col];
            #pragma unroll
            for (int q = 0; q < 4; q++)
                rs[q] += tanhf_(acc[q] + bb) * wkg[((size_t)k * NG + gq[q]) * HD + col];
        }
        #pragma unroll
        for (int q = 0; q < 4; q++) {
            float x = rs[q];
            x += __shfl_xor(x, 1); x += __shfl_xor(x, 2);
            x += __shfl_xor(x, 4); x += __shfl_xor(x, 8);
            if (l15 == 0 && nodeq[q] < NN) {
                float ev = __expf(x + mC_b[k]);
                aexp[(size_t)nodeq[q] * 4 + k] = ev;
                atomicAdd(&denom[gq[q] * 4 + k], ev);
            }
        }
    }
}

// ---------------- MegaH: hist blocks | k2 blocks ------------------------------
__global__ __launch_bounds__(256) void megaH(
    const int* __restrict__ edst, int* __restrict__ cnt,
    const float* __restrict__ v, const int* __restrict__ ngr,
    const u16* __restrict__ wsw,
    const float* __restrict__ mA_b, const float* __restrict__ mC_b,
    const float* __restrict__ wkg,
    float* __restrict__ aexp, float* __restrict__ denom)
{
    const int bid = blockIdx.x, tid = threadIdx.x;
    if (bid < MH_HIST) {
        int i = bid * 256 + tid;
        if (i < NEDG) atomicAdd(&cnt[edst[i]], 1);
    } else {
        k2_body(bid - MH_HIST, tid, v, ngr, wsw, mA_b, mC_b, wkg, aexp, denom);
    }
}

// ---------------- scan1 / scan2 ----------------------------------------------
__global__ __launch_bounds__(256) void k_scan1(const int* __restrict__ cnt,
                                               int* __restrict__ excl, int* __restrict__ bsum) {
    __shared__ int sd[256];
    int t = threadIdx.x, b = blockIdx.x;
    int base = b * 1024 + t * 4;
    int v0 = (base + 0 < NN) ? cnt[base + 0] : 0;
    int v1 = (base + 1 < NN) ? cnt[base + 1] : 0;
    int v2 = (base + 2 < NN) ? cnt[base + 2] : 0;
    int v3 = (base + 3 < NN) ? cnt[base + 3] : 0;
    int s = v0 + v1 + v2 + v3;
    sd[t] = s;
    __syncthreads();
    for (int off = 1; off < 256; off <<= 1) {
        int x = (t >= off) ? sd[t - off] : 0;
        __syncthreads();
        sd[t] += x;
        __syncthreads();
    }
    int incl = sd[t];
    int ex = incl - s;
    if (base + 0 < NN) excl[base + 0] = ex;
    if (base + 1 < NN) excl[base + 1] = ex + v0;
    if (base + 2 < NN) excl[base + 2] = ex + v0 + v1;
    if (base + 3 < NN) excl[base + 3] = ex + v0 + v1 + v2;
    if (t == 255) bsum[b] = incl;
}

#define NSCB 98
__global__ void k_scan2(int* __restrict__ bsum) {
    if (threadIdx.x == 0 && blockIdx.x == 0) {
        int run = 0;
        for (int i = 0; i < NSCB; i++) { int t = bsum[i]; bsum[i] = run; run += t; }
    }
}

// ---------------- scatter_fused: inline base + rank via atomicSub(cnt) --------
__global__ __launch_bounds__(256) void k_scatter_fused(
    const int* __restrict__ edst,
    const int* __restrict__ excl, const int* __restrict__ bsum,
    int* __restrict__ cnt, int* __restrict__ perm)
{
    int i = blockIdx.x * 256 + threadIdx.x;
    if (i < NEDG) {
        int d = edst[i];
        int rank = atomicSub(&cnt[d], 1) - 1;
        perm[excl[d] + bsum[d >> 10] + rank] = i;
    }
}

// ---------------- K3: dst-sorted merge, direct e-frag loads, run-walk ---------
#define OPW 66
__global__ __launch_bounds__(256) void k3_merge(
    const float* __restrict__ e, const float* __restrict__ v,
    const int* __restrict__ esrc, const int* __restrict__ edst,
    const int* __restrict__ perm,
    const u16* __restrict__ wsw, const float* __restrict__ K_b,
    float* __restrict__ sve)
{
    __shared__ unsigned OUTP[64 * OPW];
    __shared__ int pid[64];
    __shared__ int dsta[64];
    const int tid = threadIdx.x;
    const int e0 = blockIdx.x * 64;
    if (tid < 64) {
        int p = perm[e0 + tid];
        pid[tid] = p;
        dsta[tid] = edst[p];
    }
    const int lane = tid & 63, w = tid >> 6;
    const int l15 = lane & 15, hi = lane >> 4;
    const int rbase = w * 16;
    const int myrow = perm[e0 + rbase + l15];
    bf16x8 ae[2];
    #pragma unroll
    for (int ks = 0; ks < 2; ks++)
        ae[ks] = mk8(e + (size_t)myrow * EDIM + ks * 32 + hi * 8);
    __syncthreads();
    int sq[4];
    #pragma unroll
    for (int q = 0; q < 4; q++) sq[q] = esrc[pid[rbase + hi * 4 + q]];
    u16* OU = (u16*)OUTP;
    #pragma unroll
    for (int nt = 0; nt < 8; nt++) {
        f32x4 acc = {0.f, 0.f, 0.f, 0.f};
        acc = MFMA16(ae[0], BF(WS_KW, 8, 0, nt, lane), acc);
        acc = MFMA16(ae[1], BF(WS_KW, 8, 1, nt, lane), acc);
        int col = nt * 16 + l15;
        float kb = K_b[col];
        #pragma unroll
        for (int q = 0; q < 4; q++) {
            float val = leaky_((acc[q] + kb) * v[(size_t)sq[q] * HD + col]);
            OU[(rbase + hi * 4 + q) * (OPW * 2) + col] = f2bf(val);
        }
    }
    __syncthreads();
    {
        const int cp = tid & 63;
        const int qr = tid >> 6;
        const int r0 = qr * 16;
        int dcur = dsta[r0];
        unsigned x = OUTP[r0 * OPW + cp];
        float a0 = bfbits2f(x & 0xffff), a1 = bfbits2f(x >> 16);
        #pragma unroll
        for (int i = 1; i < 16; i++) {
            int r = r0 + i;
            int d = dsta[r];
            unsigned y = OUTP[r * OPW + cp];
            float y0 = bfbits2f(y & 0xffff), y1 = bfbits2f(y >> 16);
            if (d == dcur) { a0 += y0; a1 += y1; }
            else {
                atomicAdd(&sve[(size_t)dcur * HD + cp * 2 + 0], a0);
                atomicAdd(&sve[(size_t)dcur * HD + cp * 2 + 1], a1);
                dcur = d; a0 = y0; a1 = y1;
            }
        }
        atomicAdd(&sve[(size_t)dcur * HD + cp * 2 + 0], a0);
        atomicAdd(&sve[(size_t)dcur * HD + cp * 2 + 1], a1);
    }
}

// ---------------- K3 fallback: unsorted (global atomics, direct loads) --------
__global__ __launch_bounds__(256) void k3_edge_unsorted(
    const float* __restrict__ e, const float* __restrict__ v,
    const int* __restrict__ esrc, const int* __restrict__ edst,
    const u16* __restrict__ wsw, const float* __restrict__ K_b,
    float* __restrict__ sve)
{
    const int tid = threadIdx.x;
    const int e0 = blockIdx.x * 64;
    const int lane = tid & 63, w = tid >> 6;
    const int l15 = lane & 15, hi = lane >> 4;
    const int rbase = w * 16;
    const int myrow = e0 + rbase + l15;
    bf16x8 ae[2];
    #pragma unroll
    for (int ks = 0; ks < 2; ks++)
        ae[ks] = mk8(e + (size_t)myrow * EDIM + ks * 32 + hi * 8);
    int sq[4], dq[4];
    #pragma unroll
    for (int q = 0; q < 4; q++) {
        int ei = e0 + rbase + hi * 4 + q;
        sq[q] = esrc[ei]; dq[q] = edst[ei];
    }
    #pragma unroll
    for (int nt = 0; nt < 8; nt++) {
        f32x4 acc = {0.f, 0.f, 0.f, 0.f};
        acc = MFMA16(ae[0], BF(WS_KW, 8, 0, nt, lane), acc);
        acc = MFMA16(ae[1], BF(WS_KW, 8, 1, nt, lane), acc);
        int col = nt * 16 + l15;
        float kb = K_b[col];
        #pragma unroll
        for (int q = 0; q < 4; q++) {
            float val = leaky_((acc[q] + kb) * v[(size_t)sq[q] * HD + col]);
            atomicAdd(&sve[(size_t)dq[q] * HD + col], val);
        }
    }
}

// ---------------- K4 body: vbar ----------------------------------------------
__device__ __forceinline__ void k4_body(
    int bid, int tid,
    const float* __restrict__ v, const int* __restrict__ ngr,
    const float* __restrict__ aexp, const float* __restrict__ denom,
    float* __restrict__ vbar)
{
    const int d = tid & 127;
    const int hf = tid >> 7;
    const int n0 = bid * 32 + hf * 16;
    int gcur = -1;
    float a0 = 0.f, a1 = 0.f, a2 = 0.f, a3 = 0.f;
    float4 rd = make_float4(0.f, 0.f, 0.f, 0.f);
    for (int nd = 0; nd < 16; nd++) {
        int n = n0 + nd;
        int g = ngr[n];
        if (g != gcur) {
            if (gcur >= 0) {
                atomicAdd(&vbar[(gcur * 4 + 0) * HD + d], a0);
                atomicAdd(&vbar[(gcur * 4 + 1) * HD + d], a1);
                atomicAdd(&vbar[(gcur * 4 + 2) * HD + d], a2);
                atomicAdd(&vbar[(gcur * 4 + 3) * HD + d], a3);
                a0 = a1 = a2 = a3 = 0.f;
            }
            float4 dn = *(const float4*)&denom[g * 4];
            rd = make_float4(1.f / dn.x, 1.f / dn.y, 1.f / dn.z, 1.f / dn.w);
            gcur = g;
        }
        float4 ae = *(const float4*)&aexp[n * 4];
        float vv = v[(size_t)n * HD + d];
        a0 = fmaf(ae.x * rd.x, vv, a0);
        a1 = fmaf(ae.y * rd.y, vv, a1);
        a2 = fmaf(ae.z * rd.z, vv, a2);
        a3 = fmaf(ae.w * rd.w, vv, a3);
    }
    atomicAdd(&vbar[(gcur * 4 + 0) * HD + d], a0);
    atomicAdd(&vbar[(gcur * 4 + 1) * HD + d], a1);
    atomicAdd(&vbar[(gcur * 4 + 2) * HD + d], a2);
    atomicAdd(&vbar[(gcur * 4 + 3) * HD + d], a3);
}

// ---------------- K6 body: node update, packed bf16 state ---------------------
__device__ __forceinline__ void k6_body(
    int bid, int tid, u16* T,
    const float* __restrict__ v, const int* __restrict__ ngr,
    const float* __restrict__ sve, const u16* __restrict__ wsw,
    const float* __restrict__ E_b,
    const float* __restrict__ s2m_tab, const float* __restrict__ t2,
    const float* __restrict__ bih, const float* __restrict__ bhh,
    float* __restrict__ out_v)
{
    const int lane = tid & 63;
    const int l15 = lane & 15, hi = lane >> 4;
    const int n0 = bid * 64 + (tid >> 6) * 16;
    const int arow = min(n0 + l15, NN - 1);
    bf16x8 av[4], ax[4];
    #pragma unroll
    for (int ks = 0; ks < 4; ks++) {
        av[ks] = mk8(v   + (size_t)arow * HD + ks * 32 + hi * 8);
        ax[ks] = mk8(sve + (size_t)arow * HD + ks * 32 + hi * 8);
    }
    int gq[4], nodeq[4];
    #pragma unroll
    for (int q = 0; q < 4; q++) {
        int nd = n0 + hi * 4 + q;
        nodeq[q] = nd;
        gq[q] = ngr[min(nd, NN - 1)];
    }
    unsigned m2mp[8][2];
    #pragma unroll
    for (int nt = 0; nt < 8; nt++) {
        f32x4 acc = {0.f, 0.f, 0.f, 0.f};
        #pragma unroll
        for (int ks = 0; ks < 4; ks++) acc = MFMA16(ax[ks], BF(WS_E, 8, ks, nt, lane), acc);
        #pragma unroll
        for (int ks = 0; ks < 4; ks++) acc = MFMA16(av[ks], BF(WS_E, 8, 4 + ks, nt, lane), acc);
        float eb = E_b[nt * 16 + l15];
        float m0 = leaky_(acc[0] + eb), m1 = leaky_(acc[1] + eb);
        float m2 = leaky_(acc[2] + eb), m3 = leaky_(acc[3] + eb);
        m2mp[nt][0] = pack2bf(m0, m1);
        m2mp[nt][1] = pack2bf(m2, m3);
        int col = nt * 16 + l15;
        stg1(T, 128, hi * 4 + 0, col, (u16)(m2mp[nt][0] & 0xffff));
        stg1(T, 128, hi * 4 + 1, col, (u16)(m2mp[nt][0] >> 16));
        stg1(T, 128, hi * 4 + 2, col, (u16)(m2mp[nt][1] & 0xffff));
        stg1(T, 128, hi * 4 + 3, col, (u16)(m2mp[nt][1] >> 16));
    }
    bf16x8 am[4];
    #pragma unroll
    for (int ks = 0; ks < 4; ks++) am[ks] = ldA(T, 128, l15, ks, hi);
    unsigned hmp[8][2];
    #pragma unroll
    for (int nt = 0; nt < 8; nt++) {
        f32x4 acc = {0.f, 0.f, 0.f, 0.f};
        #pragma unroll
        for (int ks = 0; ks < 4; ks++) acc = MFMA16(am[ks], BF(WS_GA, 8, ks, nt, lane), acc);
        int col = nt * 16 + l15;
        float m2mq[4] = { bfbits2f(m2mp[nt][0] & 0xffff), bfbits2f(m2mp[nt][0] >> 16),
                          bfbits2f(m2mp[nt][1] & 0xffff), bfbits2f(m2mp[nt][1] >> 16) };
        float hm[4];
        #pragma unroll
        for (int q = 0; q < 4; q++) {
            int g = gq[q];
            float z = sigmoidf_(acc[q] + t2[(size_t)g * HD + col]);
            hm[q] = z * s2m_tab[(size_t)g * HD + col] + (1.f - z) * m2mq[q];
        }
        hmp[nt][0] = pack2bf(hm[0], hm[1]);
        hmp[nt][1] = pack2bf(hm[2], hm[3]);
        stg1(T, 128, hi * 4 + 0, col, (u16)(hmp[nt][0] & 0xffff));
        stg1(T, 128, hi * 4 + 1, col, (u16)(hmp[nt][0] >> 16));
        stg1(T, 128, hi * 4 + 2, col, (u16)(hmp[nt][1] & 0xffff));
        stg1(T, 128, hi * 4 + 3, col, (u16)(hmp[nt][1] >> 16));
    }
    bf16x8 ah[4];
    #pragma unroll
    for (int ks = 0; ks < 4; ks++) ah[ks] = ldA(T, 128, l15, ks, hi);
    #pragma unroll
    for (int nt = 0; nt < 8; nt++) {
        f32x4 air = {0.f,0.f,0.f,0.f}, aiz = {0.f,0.f,0.f,0.f}, ain = {0.f,0.f,0.f,0.f};
        f32x4 ahr = {0.f,0.f,0.f,0.f}, ahz = {0.f,0.f,0.f,0.f}, ahn = {0.f,0.f,0.f,0.f};
        #pragma unroll
        for (int ks = 0; ks < 4; ks++) {
            air = MFMA16(av[ks], BF(WS_WIH, 24, ks, nt,      lane), air);
            ahr = MFMA16(ah[ks], BF(WS_WHH, 24, ks, nt,      lane), ahr);
            aiz = MFMA16(av[ks], BF(WS_WIH, 24, ks, nt + 8,  lane), aiz);
            ahz = MFMA16(ah[ks], BF(WS_WHH, 24, ks, nt + 8,  lane), ahz);
            ain = MFMA16(av[ks], BF(WS_WIH, 24, ks, nt + 16, lane), ain);
            ahn = MFMA16(ah[ks], BF(WS_WHH, 24, ks, nt + 16, lane), ahn);
        }
        int col = nt * 16 + l15;
        float br  = bih[col] + bhh[col];
        float bz  = bih[HD + col] + bhh[HD + col];
        float bi3 = bih[2 * HD + col];
        float bh3 = bhh[2 * HD + col];
        float hmq[4] = { bfbits2f(hmp[nt][0] & 0xffff), bfbits2f(hmp[nt][0] >> 16),
                         bfbits2f(hmp[nt][1] & 0xffff), bfbits2f(hmp[nt][1] >> 16) };
        #pragma unroll
        for (int q = 0; q < 4; q++) {
            float r   = sigmoidf_(air[q] + ahr[q] + br);
            float z   = sigmoidf_(aiz[q] + ahz[q] + bz);
            float nnv = tanhf_(ain[q] + bi3 + r * (ahn[q] + bh3));
            if (nodeq[q] < NN)
                out_v[(size_t)nodeq[q] * HD + col] = (1.f - z) * nnv + z * hmq[q];
        }
    }
}

// ---------------- Mega2: k6 blocks then k4 blocks -----------------------------
__global__ __launch_bounds__(256) void mega2(
    const float* __restrict__ v, const int* __restrict__ ngr,
    const float* __restrict__ sve, const u16* __restrict__ wsw,
    const float* __restrict__ E_b,
    const float* __restrict__ s2m_tab, const float* __restrict__ t2,
    const float* __restrict__ bih, const float* __restrict__ bhh,
    const float* __restrict__ aexp, const float* __restrict__ denom,
    float* __restrict__ out_v, float* __restrict__ vbar)
{
    __shared__ u16 TT[4][16 * 128];
    const int bid = blockIdx.x, tid = threadIdx.x;
    if (bid < NB6) {
        k6_body(bid, tid, TT[tid >> 6], v, ngr, sve, wsw, E_b, s2m_tab, t2, bih, bhh, out_v);
    } else {
        k4_body(bid - NB6, tid, v, ngr, aexp, denom, vbar);
    }
}

// ---------------- K5: supernode path (fp32) -----------------------------------
__global__ __launch_bounds__(128) void k5_super(
    const float* __restrict__ s, const float* __restrict__ vbar,
    const float* __restrict__ mD_w, const float* __restrict__ mD_b,
    const float* __restrict__ B_w, const float* __restrict__ B_b,
    const float* __restrict__ s2s,
    const float* __restrict__ gsA_w, const float* __restrict__ gsA_b,
    const float* __restrict__ gsB_w, const float* __restrict__ gsB_b,
    const float* __restrict__ gsWih, const float* __restrict__ gsWhh,
    const float* __restrict__ gsbih, const float* __restrict__ gsbhh,
    float* __restrict__ out_s)
{
    __shared__ float vb[4 * HD];
    __shared__ float p[4 * HD];
    __shared__ float m2s_l[HD];
    __shared__ float s2s_l[HD];
    __shared__ float hs_l[HD];
    __shared__ float srow[HD];
    const int g = blockIdx.x, t = threadIdx.x;
    #pragma unroll
    for (int l = 0; l < 4; l++) vb[t + HD * l] = vbar[(size_t)g * 4 * HD + t + HD * l];
    srow[t]  = s[g * HD + t];
    s2s_l[t] = s2s[g * HD + t];
    __syncthreads();
    for (int k = 0; k < 4; k++) {
        float a = 0.f;
        const float* W = mD_w + k * HD * HD;
        #pragma unroll 8
        for (int i = 0; i < HD; i++) a = fmaf(vb[k * HD + i], W[i * HD + t], a);
        p[k * HD + t] = a + mD_b[k * HD + t];
    }
    __syncthreads();
    float m2s;
    {
        float a = 0.f;
        #pragma unroll 8
        for (int j = 0; j < 4 * HD; j++) a = fmaf(p[j], B_w[j * HD + t], a);
        m2s = tanhf_(a + B_b[t]);
        m2s_l[t] = m2s;
    }
    __syncthreads();
    float hs;
    {
        float za = 0.f, zb = 0.f;
        #pragma unroll 8
        for (int i = 0; i < HD; i++) {
            za = fmaf(s2s_l[i], gsA_w[i * HD + t], za);
            zb = fmaf(m2s_l[i], gsB_w[i * HD + t], zb);
        }
        float z = sigmoidf_(za + gsA_b[t] + zb + gsB_b[t]);
        hs = z * m2s + (1.f - z) * s2s_l[t];
        hs_l[t] = hs;
    }
    __syncthreads();
    float gi0 = 0.f, gh0 = 0.f, gi1 = 0.f, gh1 = 0.f, gi2 = 0.f, gh2 = 0.f;
    #pragma unroll 4
    for (int i = 0; i < HD; i++) {
        float sv = srow[i], hv = hs_l[i];
        gi0 = fmaf(sv, gsWih[i * 384 + t], gi0);
        gh0 = fmaf(hv, gsWhh[i * 384 + t], gh0);
        gi1 = fmaf(sv, gsWih[i * 384 + 128 + t], gi1);
        gh1 = fmaf(hv, gsWhh[i * 384 + 128 + t], gh1);
        gi2 = fmaf(sv, gsWih[i * 384 + 256 + t], gi2);
        gh2 = fmaf(hv, gsWhh[i * 384 + 256 + t], gh2);
    }
    float r  = sigmoidf_(gi0 + gsbih[t] + gh0 + gsbhh[t]);
    float z2 = sigmoidf_(gi1 + gsbih[128 + t] + gh1 + gsbhh[128 + t]);
    float nn = tanhf_(gi2 + gsbih[256 + t] + r * (gh2 + gsbhh[256 + t]));
    out_s[g * HD + t] = (1.f - z2) * nn + z2 * hs;
}

extern "C" void kernel_launch(void* const* d_in, const int* in_sizes, int n_in,
                              void* d_out, int out_size, void* d_ws, size_t ws_size,
                              hipStream_t stream)
{
    const float* v    = (const float*)d_in[0];
    const float* e    = (const float*)d_in[1];
    const float* s    = (const float*)d_in[2];
    const int*   esrc = (const int*)d_in[3];
    const int*   edst = (const int*)d_in[4];
    const int*   ngr  = (const int*)d_in[5];
    const float* A_w  = (const float*)d_in[6];
    const float* A_b  = (const float*)d_in[7];
    const float* mA_w = (const float*)d_in[8];
    const float* mA_b = (const float*)d_in[9];
    const float* mB_w = (const float*)d_in[10];
    const float* mB_b = (const float*)d_in[11];
    const float* mC_w = (const float*)d_in[12];
    const float* mC_b = (const float*)d_in[13];
    const float* mD_w = (const float*)d_in[14];
    const float* mD_b = (const float*)d_in[15];
    const float* B_w  = (const float*)d_in[16];
    const float* B_b  = (const float*)d_in[17];
    const float* C_w  = (const float*)d_in[18];
    const float* C_b  = (const float*)d_in[19];
    const float* K_w  = (const float*)d_in[20];
    const float* K_b  = (const float*)d_in[21];
    const float* E_w  = (const float*)d_in[22];
    const float* E_b  = (const float*)d_in[23];
    const float* gmA_w = (const float*)d_in[24];
    const float* gmA_b = (const float*)d_in[25];
    const float* gmB_w = (const float*)d_in[26];
    const float* gmB_b = (const float*)d_in[27];
    const float* gmWih = (const float*)d_in[28];
    const float* gmWhh = (const float*)d_in[29];
    const float* gmbih = (const float*)d_in[30];
    const float* gmbhh = (const float*)d_in[31];
    const float* gsA_w = (const float*)d_in[32];
    const float* gsA_b = (const float*)d_in[33];
    const float* gsB_w = (const float*)d_in[34];
    const float* gsB_b = (const float*)d_in[35];
    const float* gsWih = (const float*)d_in[36];
    const float* gsWhh = (const float*)d_in[37];
    const float* gsbih = (const float*)d_in[38];
    const float* gsbhh = (const float*)d_in[39];

    float* ws      = (float*)d_ws;
    float* sve     = ws;
    float* aexp    = sve + 12800000;
    float* denom   = aexp + 400000;
    float* wkg     = denom + 4000;
    float* s2s     = wkg + 512000;
    float* s2m_tab = s2s + 128000;
    float* t2      = s2m_tab + 128000;
    float* vbar    = t2 + 128000;
    u16*   wswz    = (u16*)(vbar + 512000);
    int*   isc     = (int*)(wswz + 221184);
    int*   cnt     = isc;
    int*   excl    = cnt + 100000;
    int*   bsum    = excl + 100000;
    int*   startp  = bsum + 128;
    int*   perm    = startp + 100000;
    const size_t NEED_SORT = ((size_t)(perm + 800000 - (int*)d_ws)) * 4;
    const bool do_sort = ws_size >= NEED_SORT;

    float* out_v = (float*)d_out;
    float* out_s = out_v + (size_t)NN * HD;

    // Mega0: wconv | k1(+vbar/denom zero) | sve/cnt zero
    mega0<<<M0_GRID, 256, 0, stream>>>(E_w, gmA_w, gmWih, gmWhh, mA_w, K_w, wswz,
                                       s, A_w, A_b, mB_w, mB_b, mC_w, C_w, C_b,
                                       gmB_w, gmA_b, gmB_b, s2s, wkg, s2m_tab, t2,
                                       vbar, denom, sve, cnt);
    // MegaH: hist | k2
    megaH<<<MH_HIST + NB2, 256, 0, stream>>>(edst, cnt, v, ngr, wswz, mA_b, mC_b,
                                             wkg, aexp, denom);
    if (do_sort) {
        k_scan1<<<NSCB, 256, 0, stream>>>(cnt, excl, bsum);
        k_scan2<<<1, 64, 0, stream>>>(bsum);
        k_scatter_fused<<<(NEDG + 255) / 256, 256, 0, stream>>>(edst, excl, bsum, cnt, perm);
        k3_merge<<<NB3, 256, 0, stream>>>(e, v, esrc, edst, perm, wswz, K_b, sve);
    } else {
        k3_edge_unsorted<<<NEDG / 64, 256, 0, stream>>>(e, v, esrc, edst, wswz, K_b, sve);
    }
    mega2<<<NB6 + NB4, 256, 0, stream>>>(v, ngr, sve, wswz, E_b, s2m_tab, t2,
                                         gmbih, gmbhh, aexp, denom, out_v, vbar);
    k5_super<<<NG, 128, 0, stream>>>(s, vbar, mD_w, mD_b, B_w, B_b, s2s,
                                     gsA_w, gsA_b, gsB_w, gsB_b,
                                     gsWih, gsWhh, gsbih, gsbhh, out_s);
}